// Round 11
// baseline (191.472 us; speedup 1.0000x reference)
//
#include <hip/hip_runtime.h>

// H=256, N1=80000, N2=20000, E1=300000. Layer 0 of the reference is dead code.
// Pipeline: prep (zero cntpair + weight transpose/cast) -> count_rank ->
// gemm0 h=x@Wg+bg (bf16 MFMA, LDS-FREE direct-fragment loads, reg prefetch;
// CSR scan fused as one extra block) -> edge_scatter (atomic-free, class-
// ordered) -> gat_sage (w=exp(lrelu()) inline; z folded into gather; unroll-2)
// -> sage_fin (lt-edges only) -> gemm1 [mean|h1a]@[Wl1;Wr1]+bias+rownorm.
// R11: the 61KB-LDS dbuf GEMM measured 94us (4x over its 20us HBM floor) --
// 2 blocks/CU + vmcnt(0) barrier drain per K-step. Direct-fragment loads need
// no LDS and no barriers: A frags per-lane from global (L1 absorbs the 4x
// wc-wave redundancy), B frags from L2-resident Wgt/Wcat.

#define NS 80000
#define ND 20000

typedef float   float4v  __attribute__((ext_vector_type(4)));
typedef float   f32x4    __attribute__((ext_vector_type(4)));
typedef __bf16  bf16x8   __attribute__((ext_vector_type(8)));
typedef unsigned short ushort8v __attribute__((ext_vector_type(8)));
typedef unsigned short ushort2v __attribute__((ext_vector_type(2)));
typedef int     int4v    __attribute__((ext_vector_type(4)));

union frag_u { ushort8v u; bf16x8 b; };

__device__ __forceinline__ float us2f(unsigned short u) {
    union { unsigned int i; float f; } x; x.i = ((unsigned)u) << 16; return x.f;
}
__device__ __forceinline__ unsigned short f2us(float f) {
    union { __bf16 b; unsigned short u; } x; x.b = (__bf16)f; return x.u;
}
__device__ __forceinline__ float lrelu02(float x) { return x > 0.f ? x : 0.2f * x; }

// ---------------------------------------------------------------------------
// prep: blocks 0..255 -> Wgt; 256..511 -> Wcat; 512.. -> zero cntpair
// ---------------------------------------------------------------------------
__global__ __launch_bounds__(256) void prep_misc(
    const float* __restrict__ Wg, const float* __restrict__ Wl,
    const float* __restrict__ Wr, unsigned short* __restrict__ Wgt,
    unsigned short* __restrict__ Wcat, int* __restrict__ zerop, int nz4)
{
    const int b = blockIdx.x, t = threadIdx.x;
    if (b < 256) {
        Wgt[b * 256 + t] = f2us(Wg[t * 256 + b]);
    } else if (b < 512) {
        const int n = b - 256;
        Wcat[n * 512 + t]       = f2us(Wl[t * 256 + n]);
        Wcat[n * 512 + 256 + t] = f2us(Wr[t * 256 + n]);
    } else {
        const int i = (b - 512) * 256 + t;
        if (i < nz4) ((int4v*)zerop)[i] = (int4v){0, 0, 0, 0};
    }
}

// ---------------------------------------------------------------------------
// count + rank within class: cntpair[2d] = #edges with s<ND, cntpair[2d+1]
// the rest. rank[i] = arrival order within (d, class).
// ---------------------------------------------------------------------------
__global__ void count_rank(const int* __restrict__ src, const int* __restrict__ dst,
                           int* __restrict__ cntpair, int* __restrict__ rank, int E)
{
    const int i = blockIdx.x * 256 + threadIdx.x;
    if (i < E) {
        const int d = dst[i];
        const int cls = (src[i] < ND) ? 0 : 1;
        rank[i] = atomicAdd(&cntpair[2 * d + cls], 1);
    }
}

// ---------------------------------------------------------------------------
// LDS-free bf16 MFMA GEMM: C[M,256] = A[M,K] @ Bt[256,K]^T
// Block: 512 thr (8 waves, 2 row x 4 col). Tile 128x256. Each lane loads its
// MFMA fragments directly from global (no LDS staging, no barriers), with a
// 1-K-step-ahead register prefetch (named A/B sets -- no dynamic indexing).
// EPI=0: write bf16 (h+bg) + fused al_s/al_d dot-products (pre-bias).
//        SCAN: block nblk runs the CSR exclusive scan over cntpair instead.
// EPI=1: +bias, row-L2-normalize, write f32 out (rows guarded by M).
// AF32:  A is f32 (x), converted to bf16 at consume time. Rows assumed < M
//        (M % 128 == 0 for gemm0).
// ---------------------------------------------------------------------------
template <int EPI, bool AF32, bool SCAN>
__global__ __launch_bounds__(512) void gemm_mfma(
    const void* __restrict__ Av, const unsigned short* __restrict__ Bt,
    int M, int K,
    unsigned short* __restrict__ hb_out,
    const float* __restrict__ avs, const float* __restrict__ avd,
    float* __restrict__ al_s, float* __restrict__ al_d,
    const float* __restrict__ bias, float* __restrict__ outp,
    int nblk, const int* __restrict__ cntpair, int* __restrict__ ptrp)
{
    __shared__ float red0[128];
    __shared__ float red1[128];
    __shared__ int   part[512];

    if (SCAN && (int)blockIdx.x >= nblk) {
        const int tid = threadIdx.x;
        const int chunk = (ND + 511) / 512;
        const int i0 = tid * chunk;
        const int i1 = min(i0 + chunk, ND);
        int s = 0;
        for (int i = i0; i < i1; ++i) s += cntpair[2*i] + cntpair[2*i+1];
        part[tid] = s;
        __syncthreads();
        for (int off = 1; off < 512; off <<= 1) {
            const int t = (tid >= off) ? part[tid - off] : 0;
            __syncthreads();
            part[tid] += t;
            __syncthreads();
        }
        int run = tid ? part[tid - 1] : 0;
        for (int i = i0; i < i1; ++i) { ptrp[i] = run; run += cntpair[2*i] + cntpair[2*i+1]; }
        if (tid == 511) ptrp[ND] = part[511];
        return;
    }

    const int tid  = threadIdx.x;
    const int lane = tid & 63;
    const int wid  = tid >> 6;
    const int wr   = wid >> 2;      // 0..1
    const int wc   = wid & 3;       // 0..3
    const int row0 = blockIdx.x * 128;
    const int lg   = lane >> 4;     // 0..3
    const int lm   = lane & 15;

    f32x4 acc[4][4] = {};
    const int nk = K >> 5;          // 8 or 16 (even)

    // fragment row/col bases (per lane)
    const int ar0 = row0 + wr*64 + lm;     // + m*16
    const int bc0 = wc*64 + lm;            // + n*16
    const int kof = lg * 8;

    float4v raA0[4], raA1[4], raB0[4], raB1[4];   // AF32 raw (unused otherwise)
    frag_u afA[4], bfA[4], afB[4], bfB[4];

    auto loadA = [&](int kt, float4v (&r0)[4], float4v (&r1)[4], frag_u (&af)[4]) {
        const int k = kt * 32 + kof;
#pragma unroll
        for (int m = 0; m < 4; ++m) {
            const int ar = ar0 + m * 16;
            if constexpr (AF32) {
                const float* p = (const float*)Av + (size_t)ar * K + k;
                r0[m] = *(const float4v*)p;
                r1[m] = *(const float4v*)(p + 4);
            } else {
                if (ar < M)
                    af[m].u = *(const ushort8v*)((const unsigned short*)Av + (size_t)ar * K + k);
                else
                    af[m].u = (ushort8v){0,0,0,0,0,0,0,0};
            }
        }
    };
    auto loadB = [&](int kt, frag_u (&bf)[4]) {
        const int k = kt * 32 + kof;
#pragma unroll
        for (int n = 0; n < 4; ++n)
            bf[n].u = *(const ushort8v*)(Bt + (size_t)(bc0 + n * 16) * K + k);
    };
    auto domfma = [&](float4v (&r0)[4], float4v (&r1)[4], frag_u (&af)[4], frag_u (&bf)[4]) {
        if constexpr (AF32) {
#pragma unroll
            for (int m = 0; m < 4; ++m) {
                af[m].u[0] = f2us(r0[m][0]); af[m].u[1] = f2us(r0[m][1]);
                af[m].u[2] = f2us(r0[m][2]); af[m].u[3] = f2us(r0[m][3]);
                af[m].u[4] = f2us(r1[m][0]); af[m].u[5] = f2us(r1[m][1]);
                af[m].u[6] = f2us(r1[m][2]); af[m].u[7] = f2us(r1[m][3]);
            }
        }
#pragma unroll
        for (int m = 0; m < 4; ++m)
#pragma unroll
            for (int n = 0; n < 4; ++n)
                acc[m][n] = __builtin_amdgcn_mfma_f32_16x16x32_bf16(
                    af[m].b, bf[n].b, acc[m][n], 0, 0, 0);
    };

    loadA(0, raA0, raA1, afA); loadB(0, bfA);
    for (int kt = 0; kt < nk; kt += 2) {
        loadA(kt + 1, raB0, raB1, afB); loadB(kt + 1, bfB);
        domfma(raA0, raA1, afA, bfA);
        if (kt + 2 < nk) { loadA(kt + 2, raA0, raA1, afA); loadB(kt + 2, bfA); }
        domfma(raB0, raB1, afB, bfB);
    }

    if constexpr (EPI == 0) {
        if (tid < 128) { red0[tid] = 0.f; red1[tid] = 0.f; }
        __syncthreads();
        float asv[4], adv[4], bgv[4];
#pragma unroll
        for (int n = 0; n < 4; ++n) {
            const int col = wc*64 + n*16 + lm;
            asv[n] = avs[col]; adv[n] = avd[col]; bgv[n] = bias[col];
        }
#pragma unroll
        for (int m = 0; m < 4; ++m) {
#pragma unroll
            for (int j = 0; j < 4; ++j) {
                const int lr = wr*64 + m*16 + lg*4 + j;
                float ps = 0.f, pd = 0.f;
#pragma unroll
                for (int n = 0; n < 4; ++n) {
                    const float v = acc[m][n][j];
                    ps += v * asv[n]; pd += v * adv[n];
                    hb_out[(size_t)(row0 + lr) * 256 + wc*64 + n*16 + lm] = f2us(v + bgv[n]);
                }
#pragma unroll
                for (int off = 1; off < 16; off <<= 1) {
                    ps += __shfl_xor(ps, off);
                    pd += __shfl_xor(pd, off);
                }
                if (lm == 0) { atomicAdd(&red0[lr], ps); atomicAdd(&red1[lr], pd); }
            }
        }
        __syncthreads();
        if (tid < 128) { al_s[row0 + tid] = red0[tid]; al_d[row0 + tid] = red1[tid]; }
    } else {
        if (tid < 128) red0[tid] = 0.f;
        __syncthreads();
        float bv[4];
#pragma unroll
        for (int n = 0; n < 4; ++n) bv[n] = bias[wc*64 + n*16 + lm];
#pragma unroll
        for (int m = 0; m < 4; ++m) {
#pragma unroll
            for (int j = 0; j < 4; ++j) {
                const int lr = wr*64 + m*16 + lg*4 + j;
                float ss = 0.f;
#pragma unroll
                for (int n = 0; n < 4; ++n) {
                    const float v = acc[m][n][j] + bv[n];
                    acc[m][n][j] = v;
                    ss += v * v;
                }
#pragma unroll
                for (int off = 1; off < 16; off <<= 1) ss += __shfl_xor(ss, off);
                if (lm == 0) atomicAdd(&red0[lr], ss);
            }
        }
        __syncthreads();
#pragma unroll
        for (int m = 0; m < 4; ++m) {
#pragma unroll
            for (int j = 0; j < 4; ++j) {
                const int lr = wr*64 + m*16 + lg*4 + j;
                const int grow = row0 + lr;
                if (grow < M) {
                    const float inv = 1.0f / fmaxf(sqrtf(red0[lr]), 1e-12f);
#pragma unroll
                    for (int n = 0; n < 4; ++n)
                        outp[(size_t)grow * 256 + wc*64 + n*16 + lm] = acc[m][n][j] * inv;
                }
            }
        }
    }
}

// ---------------------------------------------------------------------------
// scatter: atomic-free via rank; class-ordered (s<ND first within each row)
// ---------------------------------------------------------------------------
__global__ void edge_scatter(const int* __restrict__ src, const int* __restrict__ dst,
                             const int* __restrict__ ptrp, const int* __restrict__ rank,
                             const int* __restrict__ cntpair,
                             int* __restrict__ ssort, int E)
{
    const int i = blockIdx.x * 256 + threadIdx.x;
    if (i < E) {
        const int d = dst[i];
        const int s = src[i];
        const int base = ptrp[d];
        const int pos = (s < ND) ? base + rank[i]
                                 : base + cntpair[2 * d] + rank[i];
        ssort[pos] = s;
    }
}

// ---------------------------------------------------------------------------
// Fused GAT aggregation + SAGE partial sum over s>=ND neighbors.
// Block=128: 4 slots x 32 lanes; lane holds 8 channels. Weight w computed
// inline (al_s L2-resident broadcast). z folded into gather loop; unroll-2.
// Writes h1a into hcat[:,256:512] and s>=ND partial sum into hcat[:,0:256].
// ---------------------------------------------------------------------------
__global__ __launch_bounds__(128) void gat_sage(
    const unsigned short* __restrict__ hb, const float* __restrict__ al_s,
    const float* __restrict__ al_d, const int* __restrict__ ssort,
    const int* __restrict__ ptrp, unsigned short* __restrict__ hcat)
{
    __shared__ float ldsg[4][264];
    __shared__ float ldss[4][264];
    __shared__ float zp[4];
    const int v    = blockIdx.x;
    const int tid  = threadIdx.x;
    const int slot = tid >> 5;      // 0..3
    const int l32  = tid & 31;
    const int c0   = l32 * 8;
    const int p0 = ptrp[v], p1 = ptrp[v + 1];

    const float ad     = al_d[v];
    const float w_self = __expf(lrelu02(al_s[v] + ad));

    float accg[8], accs[8];
    float zpart = 0.f;
#pragma unroll
    for (int j = 0; j < 8; ++j) accs[j] = 0.f;
    if (slot == 0) {
        const ushort8v hv = *(const ushort8v*)&hb[(size_t)v * 256 + c0];
#pragma unroll
        for (int j = 0; j < 8; ++j) accg[j] = w_self * us2f(hv[j]);
    } else {
#pragma unroll
        for (int j = 0; j < 8; ++j) accg[j] = 0.f;
    }

    int p = p0 + slot;
    for (; p + 4 < p1; p += 8) {            // 2 edges per iteration
        const int s0 = ssort[p];
        const int s1 = ssort[p + 4];
        const float w0 = __expf(lrelu02(al_s[s0] + ad));
        const float w1 = __expf(lrelu02(al_s[s1] + ad));
        const ushort8v h0 = *(const ushort8v*)&hb[(size_t)s0 * 256 + c0];
        const ushort8v h1 = *(const ushort8v*)&hb[(size_t)s1 * 256 + c0];
        zpart += w0 + w1;
        const bool g0 = (s0 >= ND), g1 = (s1 >= ND);
#pragma unroll
        for (int j = 0; j < 8; ++j) {
            const float f0 = us2f(h0[j]);
            const float f1 = us2f(h1[j]);
            accg[j] = fmaf(w0, f0, accg[j]);
            accg[j] = fmaf(w1, f1, accg[j]);
            accs[j] += (g0 ? f0 : 0.f) + (g1 ? f1 : 0.f);
        }
    }
    if (p < p1) {                           // tail edge
        const int s0 = ssort[p];
        const float w0 = __expf(lrelu02(al_s[s0] + ad));
        const ushort8v h0 = *(const ushort8v*)&hb[(size_t)s0 * 256 + c0];
        zpart += w0;
        const bool g0 = (s0 >= ND);
#pragma unroll
        for (int j = 0; j < 8; ++j) {
            const float f0 = us2f(h0[j]);
            accg[j] = fmaf(w0, f0, accg[j]);
            accs[j] += g0 ? f0 : 0.f;
        }
    }

    if (l32 == 0) zp[slot] = zpart;
    *(f32x4*)&ldsg[slot][c0]     = (f32x4){accg[0], accg[1], accg[2], accg[3]};
    *(f32x4*)&ldsg[slot][c0 + 4] = (f32x4){accg[4], accg[5], accg[6], accg[7]};
    *(f32x4*)&ldss[slot][c0]     = (f32x4){accs[0], accs[1], accs[2], accs[3]};
    *(f32x4*)&ldss[slot][c0 + 4] = (f32x4){accs[4], accs[5], accs[6], accs[7]};
    __syncthreads();

    const float inv_z = 1.0f / (w_self + zp[0] + zp[1] + zp[2] + zp[3]);
    const int c = tid * 2;          // 2 channels per thread
    float rg0 = 0.f, rg1 = 0.f, rs0 = 0.f, rs1 = 0.f;
#pragma unroll
    for (int s2 = 0; s2 < 4; ++s2) {
        rg0 += ldsg[s2][c];     rg1 += ldsg[s2][c + 1];
        rs0 += ldss[s2][c];     rs1 += ldss[s2][c + 1];
    }
    *(ushort2v*)&hcat[(size_t)v * 512 + 256 + c] =
        (ushort2v){f2us(rg0 * inv_z), f2us(rg1 * inv_z)};
    *(ushort2v*)&hcat[(size_t)v * 512 + c] =
        (ushort2v){f2us(rs0), f2us(rs1)};               // psum (pre-mean)
}

// ---------------------------------------------------------------------------
// SAGE finisher: psum (bf16, in hcat[:,0:256]) += s<ND h1a gathers (class-
// ordered CSR: only the first cntpair[2v] edges, no branch); divide by
// degree; write mean back in place.
// ---------------------------------------------------------------------------
__global__ __launch_bounds__(256) void sage_fin(
    const int* __restrict__ ssort, const int* __restrict__ ptrp,
    const int* __restrict__ cntpair, unsigned short* __restrict__ hcat)
{
    const int tid   = threadIdx.x;
    const int g     = tid >> 6;                 // 0..3 (one wave per dst)
    const int v     = blockIdx.x * 4 + g;
    const int slot2 = (tid >> 5) & 1;
    const int l32   = tid & 31;
    const int c0    = l32 * 8;
    const int p0  = ptrp[v];
    const int p1l = p0 + cntpair[2 * v];        // lt-edges only
    const int deg = ptrp[v + 1] - p0;

    float acc[8];
    if (slot2 == 0) {
        const ushort8v pv = *(const ushort8v*)&hcat[(size_t)v * 512 + c0];
#pragma unroll
        for (int j = 0; j < 8; ++j) acc[j] = us2f(pv[j]);
    } else {
#pragma unroll
        for (int j = 0; j < 8; ++j) acc[j] = 0.f;
    }
    int p = p0 + slot2;
    for (; p + 2 < p1l; p += 4) {               // 2 edges per iteration
        const int s0 = ssort[p];
        const int s1 = ssort[p + 2];
        const ushort8v h0 = *(const ushort8v*)&hcat[(size_t)s0 * 512 + 256 + c0];
        const ushort8v h1 = *(const ushort8v*)&hcat[(size_t)s1 * 512 + 256 + c0];
#pragma unroll
        for (int j = 0; j < 8; ++j) acc[j] += us2f(h0[j]) + us2f(h1[j]);
    }
    if (p < p1l) {
        const int s0 = ssort[p];
        const ushort8v h0 = *(const ushort8v*)&hcat[(size_t)s0 * 512 + 256 + c0];
#pragma unroll
        for (int j = 0; j < 8; ++j) acc[j] += us2f(h0[j]);
    }
#pragma unroll
    for (int j = 0; j < 8; ++j) acc[j] += __shfl_xor(acc[j], 32);

    const float inv = (deg > 0) ? 1.0f / (float)deg : 0.f;
    if (slot2 == 0) {
        ushort8v o;
#pragma unroll
        for (int j = 0; j < 8; ++j) o[j] = f2us(acc[j] * inv);
        *(ushort8v*)&hcat[(size_t)v * 512 + c0] = o;
    }
}

// ---------------------------------------------------------------------------
extern "C" void kernel_launch(void* const* d_in, const int* in_sizes, int n_in,
                              void* d_out, int out_size, void* d_ws, size_t ws_size,
                              hipStream_t stream)
{
    const float* x    = (const float*)d_in[0];
    const float* Wg   = (const float*)d_in[1];
    const float* asrc = (const float*)d_in[2];
    const float* adst = (const float*)d_in[3];
    const float* bg   = (const float*)d_in[4];
    const float* Wl1  = (const float*)d_in[8];
    const float* bl1  = (const float*)d_in[9];
    const float* Wr1  = (const float*)d_in[10];
    const int*   src1 = (const int*)d_in[13];
    const int*   dst1 = (const int*)d_in[14];
    const int E1 = in_sizes[13];

    // workspace
    char* w = (char*)d_ws;
    unsigned short* hb   = (unsigned short*)w; w += (size_t)NS * 256 * 2;   // 40.96 MB
    unsigned short* hcat = (unsigned short*)w; w += (size_t)ND * 512 * 2;   // 20.48 MB
    unsigned short* Wgt  = (unsigned short*)w; w += 256 * 256 * 2;
    unsigned short* Wcat = (unsigned short*)w; w += 256 * 512 * 2;
    float* al_s   = (float*)w; w += (size_t)NS * 4;
    float* al_d   = (float*)w; w += (size_t)NS * 4;
    int* cntpair  = (int*)w;   w += (size_t)2 * ND * 4;
    int* ptrv     = (int*)w;   w += (size_t)(ND + 4) * 4;
    int* rank     = (int*)w;   w += (size_t)E1 * 4;
    int* ssort    = (int*)w;   w += (size_t)E1 * 4;

    const dim3 b256(256), b512(512);
    const int nz4 = 2 * ND / 4;   // cntpair in int4s

    prep_misc<<<dim3(512 + (nz4 + 255) / 256), b256, 0, stream>>>(
        Wg, Wl1, Wr1, Wgt, Wcat, cntpair, nz4);

    count_rank<<<dim3((E1 + 255) / 256), b256, 0, stream>>>(
        src1, dst1, cntpair, rank, E1);

    // h = x @ Wg + bg (bf16) with fused pre-bias al_s/al_d; scan fused
    const int nblk0 = NS / 128;
    gemm_mfma<0, true, true><<<dim3(nblk0 + 1), b512, 0, stream>>>(
        x, Wgt, NS, 256, hb, asrc, adst, al_s, al_d, bg, nullptr,
        nblk0, cntpair, ptrv);

    edge_scatter<<<dim3((E1 + 255) / 256), b256, 0, stream>>>(
        src1, dst1, ptrv, rank, cntpair, ssort, E1);

    // fused GAT aggregate + SAGE s>=ND partial sum (psum bf16 in-place)
    gat_sage<<<dim3(ND), dim3(128), 0, stream>>>(hb, al_s, al_d, ssort,
                                                 ptrv, hcat);
    // SAGE finisher: s<ND h1a gathers + divide
    sage_fin<<<dim3(ND / 4), b256, 0, stream>>>(ssort, ptrv, cntpair, hcat);

    // out = normalize([mean|h1a] @ [Wl1;Wr1] + bl1)
    gemm_mfma<1, false, false><<<dim3((ND + 127) / 128), b512, 0, stream>>>(
        hcat, Wcat, ND, 512, nullptr, nullptr, nullptr, nullptr, nullptr,
        bl1, (float*)d_out, 0, nullptr, nullptr);
}

// Round 12
// 154.576 us; speedup vs baseline: 1.2387x; 1.2387x over previous
//
#include <hip/hip_runtime.h>

// H=256, N1=80000, N2=20000, E1=300000. Layer 0 of the reference is dead code.
// Pipeline: prep (zero cntpair + weight transpose/cast) -> count_rank ->
// gemm0 h=x@Wg+bg (bf16 MFMA; CSR scan fused as one extra block) ->
// edge_scatter (atomic-free, class-ordered) -> gat_sage -> sage_fin ->
// gemm1 [mean|h1a]@[Wl1;Wr1]+bias+rownorm.
// R12 GEMM: 64x256 tile, BK=32, 512thr/8waves (each wave a 64x32 col strip,
// acc[4][2]), SINGLE-buffer 26KB LDS -> 4 blocks/CU (wave-cap) = 100% occ.
// R11 post-mortem: LDS-free direct frags = 107us at 17% occ (latency-bound);
// 61KB dbuf = 94us at 2 blocks/CU. Cross-block overlap (m114) needs many
// small co-resident blocks, not big pipelined ones.

#define NS 80000
#define ND 20000

typedef float   float4v  __attribute__((ext_vector_type(4)));
typedef float   f32x4    __attribute__((ext_vector_type(4)));
typedef __bf16  bf16x8   __attribute__((ext_vector_type(8)));
typedef unsigned short ushort8v __attribute__((ext_vector_type(8)));
typedef unsigned short ushort4v __attribute__((ext_vector_type(4)));
typedef unsigned short ushort2v __attribute__((ext_vector_type(2)));
typedef int     int4v    __attribute__((ext_vector_type(4)));

union frag_u { ushort8v u; bf16x8 b; };

__device__ __forceinline__ float us2f(unsigned short u) {
    union { unsigned int i; float f; } x; x.i = ((unsigned)u) << 16; return x.f;
}
__device__ __forceinline__ unsigned short f2us(float f) {
    union { __bf16 b; unsigned short u; } x; x.b = (__bf16)f; return x.u;
}
__device__ __forceinline__ float lrelu02(float x) { return x > 0.f ? x : 0.2f * x; }

// ---------------------------------------------------------------------------
// prep: blocks 0..255 -> Wgt; 256..511 -> Wcat; 512.. -> zero cntpair
// ---------------------------------------------------------------------------
__global__ __launch_bounds__(256) void prep_misc(
    const float* __restrict__ Wg, const float* __restrict__ Wl,
    const float* __restrict__ Wr, unsigned short* __restrict__ Wgt,
    unsigned short* __restrict__ Wcat, int* __restrict__ zerop, int nz4)
{
    const int b = blockIdx.x, t = threadIdx.x;
    if (b < 256) {
        Wgt[b * 256 + t] = f2us(Wg[t * 256 + b]);
    } else if (b < 512) {
        const int n = b - 256;
        Wcat[n * 512 + t]       = f2us(Wl[t * 256 + n]);
        Wcat[n * 512 + 256 + t] = f2us(Wr[t * 256 + n]);
    } else {
        const int i = (b - 512) * 256 + t;
        if (i < nz4) ((int4v*)zerop)[i] = (int4v){0, 0, 0, 0};
    }
}

// ---------------------------------------------------------------------------
// count + rank within class
// ---------------------------------------------------------------------------
__global__ void count_rank(const int* __restrict__ src, const int* __restrict__ dst,
                           int* __restrict__ cntpair, int* __restrict__ rank, int E)
{
    const int i = blockIdx.x * 256 + threadIdx.x;
    if (i < E) {
        const int d = dst[i];
        const int cls = (src[i] < ND) ? 0 : 1;
        rank[i] = atomicAdd(&cntpair[2 * d + cls], 1);
    }
}

// ---------------------------------------------------------------------------
// bf16 MFMA GEMM: C[M,256] = A[M,K] @ Bt[256,K]^T
// 512 thr = 8 waves; tile 64x256; wave w owns cols [w*32, w*32+32).
// BK=32 single-buffer LDS (26KB): 4 blocks/CU (wave cap) = 100% occupancy.
// Next k-tile global loads issue BEFORE the MFMA block (latency under compute)
// EPI=0: write bf16 (h+bg) + fused al_s/al_d dots. SCAN: extra block scans.
// EPI=1: +bias, row-L2-normalize, f32 out (rows guarded).
// AF32:  A is f32 (x), converted during staging; M%64==0 assumed.
// ---------------------------------------------------------------------------
template <int EPI, bool AF32, bool SCAN>
__global__ __launch_bounds__(512) void gemm_mfma(
    const void* __restrict__ Av, const unsigned short* __restrict__ Bt,
    int M, int K,
    unsigned short* __restrict__ hb_out,
    const float* __restrict__ avs, const float* __restrict__ avd,
    float* __restrict__ al_s, float* __restrict__ al_d,
    const float* __restrict__ bias, float* __restrict__ outp,
    int nblk, const int* __restrict__ cntpair, int* __restrict__ ptrp)
{
    __shared__ __align__(16) unsigned short Als[64][40];
    __shared__ __align__(16) unsigned short Bls[256][40];
    __shared__ float red0[64];
    __shared__ float red1[64];

    if (SCAN && (int)blockIdx.x >= nblk) {
        int* part = (int*)Bls;               // alias (2KB of 20KB)
        const int tid = threadIdx.x;
        const int chunk = (ND + 511) / 512;
        const int i0 = tid * chunk;
        const int i1 = min(i0 + chunk, ND);
        int s = 0;
        for (int i = i0; i < i1; ++i) s += cntpair[2*i] + cntpair[2*i+1];
        part[tid] = s;
        __syncthreads();
        for (int off = 1; off < 512; off <<= 1) {
            const int t = (tid >= off) ? part[tid - off] : 0;
            __syncthreads();
            part[tid] += t;
            __syncthreads();
        }
        int run = tid ? part[tid - 1] : 0;
        for (int i = i0; i < i1; ++i) { ptrp[i] = run; run += cntpair[2*i] + cntpair[2*i+1]; }
        if (tid == 511) ptrp[ND] = part[511];
        return;
    }

    const int tid  = threadIdx.x;
    const int lane = tid & 63;
    const int wc   = tid >> 6;          // 0..7 : column strip
    const int row0 = blockIdx.x * 64;
    const int lg   = lane >> 4;         // 0..3
    const int lm   = lane & 15;

    f32x4 acc[4][2] = {};
    const int nk = K >> 5;

    // staging indices
    const int arow = tid >> 3;          // 0..63
    const int akof = (tid & 7) * 4;     // 0,4,..,28
    const int brow = tid >> 1;          // 0..255
    const int bkof = (tid & 1) * 16;    // 0,16

    float4v ar;                         // AF32 raw
    ushort4v ai;                        // bf16 A staging
    ushort8v bvr0, bvr1;

    auto load_t = [&](int kt) {
        const int k0 = kt * 32;
        const int grow = row0 + arow;
        if constexpr (AF32) {
            ar = *(const float4v*)((const float*)Av + (size_t)grow * K + k0 + akof);
        } else {
            if (grow < M)
                ai = *(const ushort4v*)((const unsigned short*)Av + (size_t)grow * K + k0 + akof);
            else
                ai = (ushort4v){0, 0, 0, 0};
        }
        const unsigned short* bgp = Bt + (size_t)brow * K + k0 + bkof;
        bvr0 = *(const ushort8v*)bgp;
        bvr1 = *(const ushort8v*)(bgp + 8);
    };
    auto store_t = [&]() {
        if constexpr (AF32) {
            ushort4v t;
            t[0] = f2us(ar[0]); t[1] = f2us(ar[1]);
            t[2] = f2us(ar[2]); t[3] = f2us(ar[3]);
            *(ushort4v*)&Als[arow][akof] = t;
        } else {
            *(ushort4v*)&Als[arow][akof] = ai;
        }
        *(ushort8v*)&Bls[brow][bkof]     = bvr0;
        *(ushort8v*)&Bls[brow][bkof + 8] = bvr1;
    };

    load_t(0); store_t(); __syncthreads();

    for (int kt = 0; kt < nk; ++kt) {
        if (kt + 1 < nk) load_t(kt + 1);     // in flight during MFMAs
        frag_u af[4], bf[2];
#pragma unroll
        for (int m = 0; m < 4; ++m)
            af[m].u = *(const ushort8v*)&Als[m*16 + lm][lg*8];
#pragma unroll
        for (int n = 0; n < 2; ++n)
            bf[n].u = *(const ushort8v*)&Bls[wc*32 + n*16 + lm][lg*8];
#pragma unroll
        for (int m = 0; m < 4; ++m)
#pragma unroll
            for (int n = 0; n < 2; ++n)
                acc[m][n] = __builtin_amdgcn_mfma_f32_16x16x32_bf16(
                    af[m].b, bf[n].b, acc[m][n], 0, 0, 0);
        __syncthreads();                     // LDS reads done
        if (kt + 1 < nk) { store_t(); __syncthreads(); }
    }

    if constexpr (EPI == 0) {
        if (tid < 64) { red0[tid] = 0.f; red1[tid] = 0.f; }
        __syncthreads();
        float asv[2], adv[2], bgv[2];
#pragma unroll
        for (int n = 0; n < 2; ++n) {
            const int col = wc*32 + n*16 + lm;
            asv[n] = avs[col]; adv[n] = avd[col]; bgv[n] = bias[col];
        }
#pragma unroll
        for (int m = 0; m < 4; ++m) {
#pragma unroll
            for (int j = 0; j < 4; ++j) {
                const int lr = m*16 + lg*4 + j;
                float ps = 0.f, pd = 0.f;
#pragma unroll
                for (int n = 0; n < 2; ++n) {
                    const float v = acc[m][n][j];
                    ps += v * asv[n]; pd += v * adv[n];
                    hb_out[(size_t)(row0 + lr) * 256 + wc*32 + n*16 + lm] = f2us(v + bgv[n]);
                }
#pragma unroll
                for (int off = 1; off < 16; off <<= 1) {
                    ps += __shfl_xor(ps, off);
                    pd += __shfl_xor(pd, off);
                }
                if (lm == 0) { atomicAdd(&red0[lr], ps); atomicAdd(&red1[lr], pd); }
            }
        }
        __syncthreads();
        if (tid < 64) { al_s[row0 + tid] = red0[tid]; al_d[row0 + tid] = red1[tid]; }
    } else {
        if (tid < 64) red0[tid] = 0.f;
        __syncthreads();
        float bv[2];
#pragma unroll
        for (int n = 0; n < 2; ++n) bv[n] = bias[wc*32 + n*16 + lm];
#pragma unroll
        for (int m = 0; m < 4; ++m) {
#pragma unroll
            for (int j = 0; j < 4; ++j) {
                const int lr = m*16 + lg*4 + j;
                float ss = 0.f;
#pragma unroll
                for (int n = 0; n < 2; ++n) {
                    const float v = acc[m][n][j] + bv[n];
                    acc[m][n][j] = v;
                    ss += v * v;
                }
#pragma unroll
                for (int off = 1; off < 16; off <<= 1) ss += __shfl_xor(ss, off);
                if (lm == 0) atomicAdd(&red0[lr], ss);
            }
        }
        __syncthreads();
#pragma unroll
        for (int m = 0; m < 4; ++m) {
#pragma unroll
            for (int j = 0; j < 4; ++j) {
                const int lr = m*16 + lg*4 + j;
                const int grow = row0 + lr;
                if (grow < M) {
                    const float inv = 1.0f / fmaxf(sqrtf(red0[lr]), 1e-12f);
#pragma unroll
                    for (int n = 0; n < 2; ++n)
                        outp[(size_t)grow * 256 + wc*32 + n*16 + lm] = acc[m][n][j] * inv;
                }
            }
        }
    }
}

// ---------------------------------------------------------------------------
// scatter: atomic-free via rank; class-ordered (s<ND first within each row)
// ---------------------------------------------------------------------------
__global__ void edge_scatter(const int* __restrict__ src, const int* __restrict__ dst,
                             const int* __restrict__ ptrp, const int* __restrict__ rank,
                             const int* __restrict__ cntpair,
                             int* __restrict__ ssort, int E)
{
    const int i = blockIdx.x * 256 + threadIdx.x;
    if (i < E) {
        const int d = dst[i];
        const int s = src[i];
        const int base = ptrp[d];
        const int pos = (s < ND) ? base + rank[i]
                                 : base + cntpair[2 * d] + rank[i];
        ssort[pos] = s;
    }
}

// ---------------------------------------------------------------------------
// Fused GAT aggregation + SAGE partial sum over s>=ND neighbors.
// Block=128: 4 slots x 32 lanes; lane holds 8 channels. Weight w computed
// inline (al_s L2-resident broadcast). z folded into gather loop; unroll-2.
// Writes h1a into hcat[:,256:512] and s>=ND partial sum into hcat[:,0:256].
// ---------------------------------------------------------------------------
__global__ __launch_bounds__(128) void gat_sage(
    const unsigned short* __restrict__ hb, const float* __restrict__ al_s,
    const float* __restrict__ al_d, const int* __restrict__ ssort,
    const int* __restrict__ ptrp, unsigned short* __restrict__ hcat)
{
    __shared__ float ldsg[4][264];
    __shared__ float ldss[4][264];
    __shared__ float zp[4];
    const int v    = blockIdx.x;
    const int tid  = threadIdx.x;
    const int slot = tid >> 5;      // 0..3
    const int l32  = tid & 31;
    const int c0   = l32 * 8;
    const int p0 = ptrp[v], p1 = ptrp[v + 1];

    const float ad     = al_d[v];
    const float w_self = __expf(lrelu02(al_s[v] + ad));

    float accg[8], accs[8];
    float zpart = 0.f;
#pragma unroll
    for (int j = 0; j < 8; ++j) accs[j] = 0.f;
    if (slot == 0) {
        const ushort8v hv = *(const ushort8v*)&hb[(size_t)v * 256 + c0];
#pragma unroll
        for (int j = 0; j < 8; ++j) accg[j] = w_self * us2f(hv[j]);
    } else {
#pragma unroll
        for (int j = 0; j < 8; ++j) accg[j] = 0.f;
    }

    int p = p0 + slot;
    for (; p + 4 < p1; p += 8) {            // 2 edges per iteration
        const int s0 = ssort[p];
        const int s1 = ssort[p + 4];
        const float w0 = __expf(lrelu02(al_s[s0] + ad));
        const float w1 = __expf(lrelu02(al_s[s1] + ad));
        const ushort8v h0 = *(const ushort8v*)&hb[(size_t)s0 * 256 + c0];
        const ushort8v h1 = *(const ushort8v*)&hb[(size_t)s1 * 256 + c0];
        zpart += w0 + w1;
        const bool g0 = (s0 >= ND), g1 = (s1 >= ND);
#pragma unroll
        for (int j = 0; j < 8; ++j) {
            const float f0 = us2f(h0[j]);
            const float f1 = us2f(h1[j]);
            accg[j] = fmaf(w0, f0, accg[j]);
            accg[j] = fmaf(w1, f1, accg[j]);
            accs[j] += (g0 ? f0 : 0.f) + (g1 ? f1 : 0.f);
        }
    }
    if (p < p1) {                           // tail edge
        const int s0 = ssort[p];
        const float w0 = __expf(lrelu02(al_s[s0] + ad));
        const ushort8v h0 = *(const ushort8v*)&hb[(size_t)s0 * 256 + c0];
        zpart += w0;
        const bool g0 = (s0 >= ND);
#pragma unroll
        for (int j = 0; j < 8; ++j) {
            const float f0 = us2f(h0[j]);
            accg[j] = fmaf(w0, f0, accg[j]);
            accs[j] += g0 ? f0 : 0.f;
        }
    }

    if (l32 == 0) zp[slot] = zpart;
    *(f32x4*)&ldsg[slot][c0]     = (f32x4){accg[0], accg[1], accg[2], accg[3]};
    *(f32x4*)&ldsg[slot][c0 + 4] = (f32x4){accg[4], accg[5], accg[6], accg[7]};
    *(f32x4*)&ldss[slot][c0]     = (f32x4){accs[0], accs[1], accs[2], accs[3]};
    *(f32x4*)&ldss[slot][c0 + 4] = (f32x4){accs[4], accs[5], accs[6], accs[7]};
    __syncthreads();

    const float inv_z = 1.0f / (w_self + zp[0] + zp[1] + zp[2] + zp[3]);
    const int c = tid * 2;          // 2 channels per thread
    float rg0 = 0.f, rg1 = 0.f, rs0 = 0.f, rs1 = 0.f;
#pragma unroll
    for (int s2 = 0; s2 < 4; ++s2) {
        rg0 += ldsg[s2][c];     rg1 += ldsg[s2][c + 1];
        rs0 += ldss[s2][c];     rs1 += ldss[s2][c + 1];
    }
    *(ushort2v*)&hcat[(size_t)v * 512 + 256 + c] =
        (ushort2v){f2us(rg0 * inv_z), f2us(rg1 * inv_z)};
    *(ushort2v*)&hcat[(size_t)v * 512 + c] =
        (ushort2v){f2us(rs0), f2us(rs1)};               // psum (pre-mean)
}

// ---------------------------------------------------------------------------
// SAGE finisher: psum (bf16, in hcat[:,0:256]) += s<ND h1a gathers (class-
// ordered CSR: only first cntpair[2v] edges, no branch); divide by degree.
// ---------------------------------------------------------------------------
__global__ __launch_bounds__(256) void sage_fin(
    const int* __restrict__ ssort, const int* __restrict__ ptrp,
    const int* __restrict__ cntpair, unsigned short* __restrict__ hcat)
{
    const int tid   = threadIdx.x;
    const int g     = tid >> 6;                 // 0..3 (one wave per dst)
    const int v     = blockIdx.x * 4 + g;
    const int slot2 = (tid >> 5) & 1;
    const int l32   = tid & 31;
    const int c0    = l32 * 8;
    const int p0  = ptrp[v];
    const int p1l = p0 + cntpair[2 * v];        // lt-edges only
    const int deg = ptrp[v + 1] - p0;

    float acc[8];
    if (slot2 == 0) {
        const ushort8v pv = *(const ushort8v*)&hcat[(size_t)v * 512 + c0];
#pragma unroll
        for (int j = 0; j < 8; ++j) acc[j] = us2f(pv[j]);
    } else {
#pragma unroll
        for (int j = 0; j < 8; ++j) acc[j] = 0.f;
    }
    int p = p0 + slot2;
    for (; p + 2 < p1l; p += 4) {               // 2 edges per iteration
        const int s0 = ssort[p];
        const int s1 = ssort[p + 2];
        const ushort8v h0 = *(const ushort8v*)&hcat[(size_t)s0 * 512 + 256 + c0];
        const ushort8v h1 = *(const ushort8v*)&hcat[(size_t)s1 * 512 + 256 + c0];
#pragma unroll
        for (int j = 0; j < 8; ++j) acc[j] += us2f(h0[j]) + us2f(h1[j]);
    }
    if (p < p1l) {
        const int s0 = ssort[p];
        const ushort8v h0 = *(const ushort8v*)&hcat[(size_t)s0 * 512 + 256 + c0];
#pragma unroll
        for (int j = 0; j < 8; ++j) acc[j] += us2f(h0[j]);
    }
#pragma unroll
    for (int j = 0; j < 8; ++j) acc[j] += __shfl_xor(acc[j], 32);

    const float inv = (deg > 0) ? 1.0f / (float)deg : 0.f;
    if (slot2 == 0) {
        ushort8v o;
#pragma unroll
        for (int j = 0; j < 8; ++j) o[j] = f2us(acc[j] * inv);
        *(ushort8v*)&hcat[(size_t)v * 512 + c0] = o;
    }
}

// ---------------------------------------------------------------------------
extern "C" void kernel_launch(void* const* d_in, const int* in_sizes, int n_in,
                              void* d_out, int out_size, void* d_ws, size_t ws_size,
                              hipStream_t stream)
{
    const float* x    = (const float*)d_in[0];
    const float* Wg   = (const float*)d_in[1];
    const float* asrc = (const float*)d_in[2];
    const float* adst = (const float*)d_in[3];
    const float* bg   = (const float*)d_in[4];
    const float* Wl1  = (const float*)d_in[8];
    const float* bl1  = (const float*)d_in[9];
    const float* Wr1  = (const float*)d_in[10];
    const int*   src1 = (const int*)d_in[13];
    const int*   dst1 = (const int*)d_in[14];
    const int E1 = in_sizes[13];

    // workspace
    char* w = (char*)d_ws;
    unsigned short* hb   = (unsigned short*)w; w += (size_t)NS * 256 * 2;   // 40.96 MB
    unsigned short* hcat = (unsigned short*)w; w += (size_t)ND * 512 * 2;   // 20.48 MB
    unsigned short* Wgt  = (unsigned short*)w; w += 256 * 256 * 2;
    unsigned short* Wcat = (unsigned short*)w; w += 256 * 512 * 2;
    float* al_s   = (float*)w; w += (size_t)NS * 4;
    float* al_d   = (float*)w; w += (size_t)NS * 4;
    int* cntpair  = (int*)w;   w += (size_t)2 * ND * 4;
    int* ptrv     = (int*)w;   w += (size_t)(ND + 4) * 4;
    int* rank     = (int*)w;   w += (size_t)E1 * 4;
    int* ssort    = (int*)w;   w += (size_t)E1 * 4;

    const dim3 b256(256), b512(512);
    const int nz4 = 2 * ND / 4;   // cntpair in int4s

    prep_misc<<<dim3(512 + (nz4 + 255) / 256), b256, 0, stream>>>(
        Wg, Wl1, Wr1, Wgt, Wcat, cntpair, nz4);

    count_rank<<<dim3((E1 + 255) / 256), b256, 0, stream>>>(
        src1, dst1, cntpair, rank, E1);

    // h = x @ Wg + bg (bf16) with fused pre-bias al_s/al_d; scan fused
    const int nblk0 = NS / 64;
    gemm_mfma<0, true, true><<<dim3(nblk0 + 1), b512, 0, stream>>>(
        x, Wgt, NS, 256, hb, asrc, adst, al_s, al_d, bg, nullptr,
        nblk0, cntpair, ptrv);

    edge_scatter<<<dim3((E1 + 255) / 256), b256, 0, stream>>>(
        src1, dst1, ptrv, rank, cntpair, ssort, E1);

    // fused GAT aggregate + SAGE s>=ND partial sum (psum bf16 in-place)
    gat_sage<<<dim3(ND), dim3(128), 0, stream>>>(hb, al_s, al_d, ssort,
                                                 ptrv, hcat);
    // SAGE finisher: s<ND h1a gathers + divide
    sage_fin<<<dim3(ND / 4), b256, 0, stream>>>(ssort, ptrv, cntpair, hcat);

    // out = normalize([mean|h1a] @ [Wl1;Wr1] + bl1)
    gemm_mfma<1, false, false><<<dim3((ND + 63) / 64), b512, 0, stream>>>(
        hcat, Wcat, ND, 512, nullptr, nullptr, nullptr, nullptr, nullptr,
        bl1, (float*)d_out, 0, nullptr, nullptr);
}

// Round 13
// 152.494 us; speedup vs baseline: 1.2556x; 1.0137x over previous
//
#include <hip/hip_runtime.h>

// H=256, N1=80000, N2=20000, E1=300000. Layer 0 of the reference is dead code.
// Pipeline: prep -> count_rank -> gemm0 h=x@Wg+bg (bf16 MFMA; scan fused) ->
// edge_scatter -> gat_sage -> sage_fin -> gemm1 (+bias+rownorm).
// R13 GEMM: 256thr/4 waves, tile 64x256 (wave = 64-col strip, acc[4][4]).
// B frags read DIRECTLY from global (Wgt/Wcat are L2-resident; every block
// reads the same 128-256KB). LDS = A-only double-buffer (10KB) -> up to 8
// blocks/CU; ONE barrier per K-step (store to buf^1 while buf read).
// R11/R12 post-mortem: all big-LDS/no-LDS variants ~90-107us, MfmaUtil 4%,
// everything idle -> latency-bound; this maximizes co-resident blocks and
// kills B staging traffic (75KB/kstep -> 0).

#define NS 80000
#define ND 20000

typedef float   float4v  __attribute__((ext_vector_type(4)));
typedef float   f32x4    __attribute__((ext_vector_type(4)));
typedef __bf16  bf16x8   __attribute__((ext_vector_type(8)));
typedef unsigned short ushort8v __attribute__((ext_vector_type(8)));
typedef unsigned short ushort2v __attribute__((ext_vector_type(2)));
typedef int     int4v    __attribute__((ext_vector_type(4)));

union frag_u { ushort8v u; bf16x8 b; };

__device__ __forceinline__ float us2f(unsigned short u) {
    union { unsigned int i; float f; } x; x.i = ((unsigned)u) << 16; return x.f;
}
__device__ __forceinline__ unsigned short f2us(float f) {
    union { __bf16 b; unsigned short u; } x; x.b = (__bf16)f; return x.u;
}
__device__ __forceinline__ float lrelu02(float x) { return x > 0.f ? x : 0.2f * x; }

// ---------------------------------------------------------------------------
// prep: blocks 0..255 -> Wgt; 256..511 -> Wcat; 512.. -> zero cntpair
// ---------------------------------------------------------------------------
__global__ __launch_bounds__(256) void prep_misc(
    const float* __restrict__ Wg, const float* __restrict__ Wl,
    const float* __restrict__ Wr, unsigned short* __restrict__ Wgt,
    unsigned short* __restrict__ Wcat, int* __restrict__ zerop, int nz4)
{
    const int b = blockIdx.x, t = threadIdx.x;
    if (b < 256) {
        Wgt[b * 256 + t] = f2us(Wg[t * 256 + b]);
    } else if (b < 512) {
        const int n = b - 256;
        Wcat[n * 512 + t]       = f2us(Wl[t * 256 + n]);
        Wcat[n * 512 + 256 + t] = f2us(Wr[t * 256 + n]);
    } else {
        const int i = (b - 512) * 256 + t;
        if (i < nz4) ((int4v*)zerop)[i] = (int4v){0, 0, 0, 0};
    }
}

// ---------------------------------------------------------------------------
// count + rank within class
// ---------------------------------------------------------------------------
__global__ void count_rank(const int* __restrict__ src, const int* __restrict__ dst,
                           int* __restrict__ cntpair, int* __restrict__ rank, int E)
{
    const int i = blockIdx.x * 256 + threadIdx.x;
    if (i < E) {
        const int d = dst[i];
        const int cls = (src[i] < ND) ? 0 : 1;
        rank[i] = atomicAdd(&cntpair[2 * d + cls], 1);
    }
}

// ---------------------------------------------------------------------------
// bf16 MFMA GEMM: C[M,256] = A[M,K] @ Bt[256,K]^T
// 256 thr = 4 waves; tile 64x256; wave wc owns cols [wc*64, wc*64+64).
// A-only dbuf LDS (10KB); B frags direct from global; 1 barrier per K-step.
// EPI=0: write bf16 (h+bg) + fused al_s/al_d dots. SCAN: extra block scans.
// EPI=1: +bias, row-L2-normalize, f32 out (rows guarded).
// AF32: A is f32 (x), cvt during staging; M%64==0 assumed for AF32 path.
// ---------------------------------------------------------------------------
template <int EPI, bool AF32, bool SCAN>
__global__ __launch_bounds__(256, 4) void gemm_mfma(
    const void* __restrict__ Av, const unsigned short* __restrict__ Bt,
    int M, int K,
    unsigned short* __restrict__ hb_out,
    const float* __restrict__ avs, const float* __restrict__ avd,
    float* __restrict__ al_s, float* __restrict__ al_d,
    const float* __restrict__ bias, float* __restrict__ outp,
    int nblk, const int* __restrict__ cntpair, int* __restrict__ ptrp)
{
    __shared__ __align__(16) unsigned short Als[2][64][40];
    __shared__ float red0[64];
    __shared__ float red1[64];
    __shared__ int   part[256];

    if (SCAN && (int)blockIdx.x >= nblk) {
        const int tid = threadIdx.x;
        const int chunk = (ND + 255) / 256;
        const int i0 = tid * chunk;
        const int i1 = min(i0 + chunk, ND);
        int s = 0;
        for (int i = i0; i < i1; ++i) s += cntpair[2*i] + cntpair[2*i+1];
        part[tid] = s;
        __syncthreads();
        for (int off = 1; off < 256; off <<= 1) {
            const int t = (tid >= off) ? part[tid - off] : 0;
            __syncthreads();
            part[tid] += t;
            __syncthreads();
        }
        int run = tid ? part[tid - 1] : 0;
        for (int i = i0; i < i1; ++i) { ptrp[i] = run; run += cntpair[2*i] + cntpair[2*i+1]; }
        if (tid == 255) ptrp[ND] = part[255];
        return;
    }

    const int tid  = threadIdx.x;
    const int lane = tid & 63;
    const int wc   = tid >> 6;          // 0..3 : 64-col strip
    const int row0 = blockIdx.x * 64;
    const int lg   = lane >> 4;         // 0..3
    const int lm   = lane & 15;

    f32x4 acc[4][4] = {};
    const int nk = K >> 5;

    // A staging: thread -> row tid>>2 (0..63), k-offset (tid&3)*8
    const int arow = tid >> 2;
    const int akof = (tid & 3) * 8;

    float4v ar0, ar1;                   // AF32 raw (32B/thread)
    ushort8v ai;                        // bf16 raw (16B/thread)

    auto loadA = [&](int kt) {
        const int k0 = kt * 32 + akof;
        const int grow = row0 + arow;
        if constexpr (AF32) {
            const float* p = (const float*)Av + (size_t)grow * K + k0;
            ar0 = *(const float4v*)p;
            ar1 = *(const float4v*)(p + 4);
        } else {
            if (grow < M)
                ai = *(const ushort8v*)((const unsigned short*)Av + (size_t)grow * K + k0);
            else
                ai = (ushort8v){0,0,0,0,0,0,0,0};
        }
    };
    auto storeA = [&](int b) {
        if constexpr (AF32) {
            ushort8v t;
            t[0] = f2us(ar0[0]); t[1] = f2us(ar0[1]); t[2] = f2us(ar0[2]); t[3] = f2us(ar0[3]);
            t[4] = f2us(ar1[0]); t[5] = f2us(ar1[1]); t[6] = f2us(ar1[2]); t[7] = f2us(ar1[3]);
            *(ushort8v*)&Als[b][arow][akof] = t;
        } else {
            *(ushort8v*)&Als[b][arow][akof] = ai;
        }
    };

    loadA(0); storeA(0); __syncthreads();
    if (nk > 1) loadA(1);
    int cur = 0;

    for (int kt = 0; kt < nk; ++kt) {
        // B frags straight from global (L1/L2-resident weight)
        frag_u bf[4];
        {
            const int k = kt * 32 + lg * 8;
#pragma unroll
            for (int n = 0; n < 4; ++n)
                bf[n].u = *(const ushort8v*)(Bt + (size_t)(wc*64 + n*16 + lm) * K + k);
        }
        frag_u af[4];
#pragma unroll
        for (int m = 0; m < 4; ++m)
            af[m].u = *(const ushort8v*)&Als[cur][m*16 + lm][lg*8];
#pragma unroll
        for (int m = 0; m < 4; ++m)
#pragma unroll
            for (int n = 0; n < 4; ++n)
                acc[m][n] = __builtin_amdgcn_mfma_f32_16x16x32_bf16(
                    af[m].b, bf[n].b, acc[m][n], 0, 0, 0);
        if (kt + 1 < nk) {
            storeA(cur ^ 1);                 // regs hold tile kt+1
            if (kt + 2 < nk) loadA(kt + 2);  // issue under next MFMAs
            __syncthreads();
            cur ^= 1;
        }
    }

    if constexpr (EPI == 0) {
        if (tid < 64) { red0[tid] = 0.f; red1[tid] = 0.f; }
        __syncthreads();
        float asv[4], adv[4], bgv[4];
#pragma unroll
        for (int n = 0; n < 4; ++n) {
            const int col = wc*64 + n*16 + lm;
            asv[n] = avs[col]; adv[n] = avd[col]; bgv[n] = bias[col];
        }
#pragma unroll
        for (int m = 0; m < 4; ++m) {
#pragma unroll
            for (int j = 0; j < 4; ++j) {
                const int lr = m*16 + lg*4 + j;
                float ps = 0.f, pd = 0.f;
#pragma unroll
                for (int n = 0; n < 4; ++n) {
                    const float v = acc[m][n][j];
                    ps += v * asv[n]; pd += v * adv[n];
                    hb_out[(size_t)(row0 + lr) * 256 + wc*64 + n*16 + lm] = f2us(v + bgv[n]);
                }
#pragma unroll
                for (int off = 1; off < 16; off <<= 1) {
                    ps += __shfl_xor(ps, off);
                    pd += __shfl_xor(pd, off);
                }
                if (lm == 0) { atomicAdd(&red0[lr], ps); atomicAdd(&red1[lr], pd); }
            }
        }
        __syncthreads();
        if (tid < 64) { al_s[row0 + tid] = red0[tid]; al_d[row0 + tid] = red1[tid]; }
    } else {
        if (tid < 64) red0[tid] = 0.f;
        __syncthreads();
        float bv[4];
#pragma unroll
        for (int n = 0; n < 4; ++n) bv[n] = bias[wc*64 + n*16 + lm];
#pragma unroll
        for (int m = 0; m < 4; ++m) {
#pragma unroll
            for (int j = 0; j < 4; ++j) {
                const int lr = m*16 + lg*4 + j;
                float ss = 0.f;
#pragma unroll
                for (int n = 0; n < 4; ++n) {
                    const float v = acc[m][n][j] + bv[n];
                    acc[m][n][j] = v;
                    ss += v * v;
                }
#pragma unroll
                for (int off = 1; off < 16; off <<= 1) ss += __shfl_xor(ss, off);
                if (lm == 0) atomicAdd(&red0[lr], ss);
            }
        }
        __syncthreads();
#pragma unroll
        for (int m = 0; m < 4; ++m) {
#pragma unroll
            for (int j = 0; j < 4; ++j) {
                const int lr = m*16 + lg*4 + j;
                const int grow = row0 + lr;
                if (grow < M) {
                    const float inv = 1.0f / fmaxf(sqrtf(red0[lr]), 1e-12f);
#pragma unroll
                    for (int n = 0; n < 4; ++n)
                        outp[(size_t)grow * 256 + wc*64 + n*16 + lm] = acc[m][n][j] * inv;
                }
            }
        }
    }
}

// ---------------------------------------------------------------------------
// scatter: atomic-free via rank; class-ordered (s<ND first within each row)
// ---------------------------------------------------------------------------
__global__ void edge_scatter(const int* __restrict__ src, const int* __restrict__ dst,
                             const int* __restrict__ ptrp, const int* __restrict__ rank,
                             const int* __restrict__ cntpair,
                             int* __restrict__ ssort, int E)
{
    const int i = blockIdx.x * 256 + threadIdx.x;
    if (i < E) {
        const int d = dst[i];
        const int s = src[i];
        const int base = ptrp[d];
        const int pos = (s < ND) ? base + rank[i]
                                 : base + cntpair[2 * d] + rank[i];
        ssort[pos] = s;
    }
}

// ---------------------------------------------------------------------------
// Fused GAT aggregation + SAGE partial sum over s>=ND neighbors.
// Block=128: 4 slots x 32 lanes; lane holds 8 channels. Weight w computed
// inline (al_s L2-resident broadcast). z folded into gather loop; unroll-2.
// Writes h1a into hcat[:,256:512] and s>=ND partial sum into hcat[:,0:256].
// ---------------------------------------------------------------------------
__global__ __launch_bounds__(128) void gat_sage(
    const unsigned short* __restrict__ hb, const float* __restrict__ al_s,
    const float* __restrict__ al_d, const int* __restrict__ ssort,
    const int* __restrict__ ptrp, unsigned short* __restrict__ hcat)
{
    __shared__ float ldsg[4][264];
    __shared__ float ldss[4][264];
    __shared__ float zp[4];
    const int v    = blockIdx.x;
    const int tid  = threadIdx.x;
    const int slot = tid >> 5;      // 0..3
    const int l32  = tid & 31;
    const int c0   = l32 * 8;
    const int p0 = ptrp[v], p1 = ptrp[v + 1];

    const float ad     = al_d[v];
    const float w_self = __expf(lrelu02(al_s[v] + ad));

    float accg[8], accs[8];
    float zpart = 0.f;
#pragma unroll
    for (int j = 0; j < 8; ++j) accs[j] = 0.f;
    if (slot == 0) {
        const ushort8v hv = *(const ushort8v*)&hb[(size_t)v * 256 + c0];
#pragma unroll
        for (int j = 0; j < 8; ++j) accg[j] = w_self * us2f(hv[j]);
    } else {
#pragma unroll
        for (int j = 0; j < 8; ++j) accg[j] = 0.f;
    }

    int p = p0 + slot;
    for (; p + 4 < p1; p += 8) {            // 2 edges per iteration
        const int s0 = ssort[p];
        const int s1 = ssort[p + 4];
        const float w0 = __expf(lrelu02(al_s[s0] + ad));
        const float w1 = __expf(lrelu02(al_s[s1] + ad));
        const ushort8v h0 = *(const ushort8v*)&hb[(size_t)s0 * 256 + c0];
        const ushort8v h1 = *(const ushort8v*)&hb[(size_t)s1 * 256 + c0];
        zpart += w0 + w1;
        const bool g0 = (s0 >= ND), g1 = (s1 >= ND);
#pragma unroll
        for (int j = 0; j < 8; ++j) {
            const float f0 = us2f(h0[j]);
            const float f1 = us2f(h1[j]);
            accg[j] = fmaf(w0, f0, accg[j]);
            accg[j] = fmaf(w1, f1, accg[j]);
            accs[j] += (g0 ? f0 : 0.f) + (g1 ? f1 : 0.f);
        }
    }
    if (p < p1) {                           // tail edge
        const int s0 = ssort[p];
        const float w0 = __expf(lrelu02(al_s[s0] + ad));
        const ushort8v h0 = *(const ushort8v*)&hb[(size_t)s0 * 256 + c0];
        zpart += w0;
        const bool g0 = (s0 >= ND);
#pragma unroll
        for (int j = 0; j < 8; ++j) {
            const float f0 = us2f(h0[j]);
            accg[j] = fmaf(w0, f0, accg[j]);
            accs[j] += g0 ? f0 : 0.f;
        }
    }

    if (l32 == 0) zp[slot] = zpart;
    *(f32x4*)&ldsg[slot][c0]     = (f32x4){accg[0], accg[1], accg[2], accg[3]};
    *(f32x4*)&ldsg[slot][c0 + 4] = (f32x4){accg[4], accg[5], accg[6], accg[7]};
    *(f32x4*)&ldss[slot][c0]     = (f32x4){accs[0], accs[1], accs[2], accs[3]};
    *(f32x4*)&ldss[slot][c0 + 4] = (f32x4){accs[4], accs[5], accs[6], accs[7]};
    __syncthreads();

    const float inv_z = 1.0f / (w_self + zp[0] + zp[1] + zp[2] + zp[3]);
    const int c = tid * 2;          // 2 channels per thread
    float rg0 = 0.f, rg1 = 0.f, rs0 = 0.f, rs1 = 0.f;
#pragma unroll
    for (int s2 = 0; s2 < 4; ++s2) {
        rg0 += ldsg[s2][c];     rg1 += ldsg[s2][c + 1];
        rs0 += ldss[s2][c];     rs1 += ldss[s2][c + 1];
    }
    *(ushort2v*)&hcat[(size_t)v * 512 + 256 + c] =
        (ushort2v){f2us(rg0 * inv_z), f2us(rg1 * inv_z)};
    *(ushort2v*)&hcat[(size_t)v * 512 + c] =
        (ushort2v){f2us(rs0), f2us(rs1)};               // psum (pre-mean)
}

// ---------------------------------------------------------------------------
// SAGE finisher: psum (bf16, in hcat[:,0:256]) += s<ND h1a gathers (class-
// ordered CSR: only first cntpair[2v] edges, no branch); divide by degree.
// ---------------------------------------------------------------------------
__global__ __launch_bounds__(256) void sage_fin(
    const int* __restrict__ ssort, const int* __restrict__ ptrp,
    const int* __restrict__ cntpair, unsigned short* __restrict__ hcat)
{
    const int tid   = threadIdx.x;
    const int g     = tid >> 6;                 // 0..3 (one wave per dst)
    const int v     = blockIdx.x * 4 + g;
    const int slot2 = (tid >> 5) & 1;
    const int l32   = tid & 31;
    const int c0    = l32 * 8;
    const int p0  = ptrp[v];
    const int p1l = p0 + cntpair[2 * v];        // lt-edges only
    const int deg = ptrp[v + 1] - p0;

    float acc[8];
    if (slot2 == 0) {
        const ushort8v pv = *(const ushort8v*)&hcat[(size_t)v * 512 + c0];
#pragma unroll
        for (int j = 0; j < 8; ++j) acc[j] = us2f(pv[j]);
    } else {
#pragma unroll
        for (int j = 0; j < 8; ++j) acc[j] = 0.f;
    }
    int p = p0 + slot2;
    for (; p + 2 < p1l; p += 4) {               // 2 edges per iteration
        const int s0 = ssort[p];
        const int s1 = ssort[p + 2];
        const ushort8v h0 = *(const ushort8v*)&hcat[(size_t)s0 * 512 + 256 + c0];
        const ushort8v h1 = *(const ushort8v*)&hcat[(size_t)s1 * 512 + 256 + c0];
#pragma unroll
        for (int j = 0; j < 8; ++j) acc[j] += us2f(h0[j]) + us2f(h1[j]);
    }
    if (p < p1l) {
        const int s0 = ssort[p];
        const ushort8v h0 = *(const ushort8v*)&hcat[(size_t)s0 * 512 + 256 + c0];
#pragma unroll
        for (int j = 0; j < 8; ++j) acc[j] += us2f(h0[j]);
    }
#pragma unroll
    for (int j = 0; j < 8; ++j) acc[j] += __shfl_xor(acc[j], 32);

    const float inv = (deg > 0) ? 1.0f / (float)deg : 0.f;
    if (slot2 == 0) {
        ushort8v o;
#pragma unroll
        for (int j = 0; j < 8; ++j) o[j] = f2us(acc[j] * inv);
        *(ushort8v*)&hcat[(size_t)v * 512 + c0] = o;
    }
}

// ---------------------------------------------------------------------------
extern "C" void kernel_launch(void* const* d_in, const int* in_sizes, int n_in,
                              void* d_out, int out_size, void* d_ws, size_t ws_size,
                              hipStream_t stream)
{
    const float* x    = (const float*)d_in[0];
    const float* Wg   = (const float*)d_in[1];
    const float* asrc = (const float*)d_in[2];
    const float* adst = (const float*)d_in[3];
    const float* bg   = (const float*)d_in[4];
    const float* Wl1  = (const float*)d_in[8];
    const float* bl1  = (const float*)d_in[9];
    const float* Wr1  = (const float*)d_in[10];
    const int*   src1 = (const int*)d_in[13];
    const int*   dst1 = (const int*)d_in[14];
    const int E1 = in_sizes[13];

    // workspace
    char* w = (char*)d_ws;
    unsigned short* hb   = (unsigned short*)w; w += (size_t)NS * 256 * 2;   // 40.96 MB
    unsigned short* hcat = (unsigned short*)w; w += (size_t)ND * 512 * 2;   // 20.48 MB
    unsigned short* Wgt  = (unsigned short*)w; w += 256 * 256 * 2;
    unsigned short* Wcat = (unsigned short*)w; w += 256 * 512 * 2;
    float* al_s   = (float*)w; w += (size_t)NS * 4;
    float* al_d   = (float*)w; w += (size_t)NS * 4;
    int* cntpair  = (int*)w;   w += (size_t)2 * ND * 4;
    int* ptrv     = (int*)w;   w += (size_t)(ND + 4) * 4;
    int* rank     = (int*)w;   w += (size_t)E1 * 4;
    int* ssort    = (int*)w;   w += (size_t)E1 * 4;

    const dim3 b256(256);
    const int nz4 = 2 * ND / 4;   // cntpair in int4s

    prep_misc<<<dim3(512 + (nz4 + 255) / 256), b256, 0, stream>>>(
        Wg, Wl1, Wr1, Wgt, Wcat, cntpair, nz4);

    count_rank<<<dim3((E1 + 255) / 256), b256, 0, stream>>>(
        src1, dst1, cntpair, rank, E1);

    // h = x @ Wg + bg (bf16) with fused pre-bias al_s/al_d; scan fused
    const int nblk0 = NS / 64;
    gemm_mfma<0, true, true><<<dim3(nblk0 + 1), b256, 0, stream>>>(
        x, Wgt, NS, 256, hb, asrc, adst, al_s, al_d, bg, nullptr,
        nblk0, cntpair, ptrv);

    edge_scatter<<<dim3((E1 + 255) / 256), b256, 0, stream>>>(
        src1, dst1, ptrv, rank, cntpair, ssort, E1);

    // fused GAT aggregate + SAGE s>=ND partial sum (psum bf16 in-place)
    gat_sage<<<dim3(ND), dim3(128), 0, stream>>>(hb, al_s, al_d, ssort,
                                                 ptrv, hcat);
    // SAGE finisher: s<ND h1a gathers + divide
    sage_fin<<<dim3(ND / 4), b256, 0, stream>>>(ssort, ptrv, cntpair, hcat);

    // out = normalize([mean|h1a] @ [Wl1;Wr1] + bl1)
    gemm_mfma<1, false, false><<<dim3((ND + 63) / 64), b256, 0, stream>>>(
        hcat, Wcat, ND, 512, nullptr, nullptr, nullptr, nullptr, nullptr,
        bl1, (float*)d_out, 0, nullptr, nullptr);
}

// Round 14
// 146.248 us; speedup vs baseline: 1.3092x; 1.0427x over previous
//
#include <hip/hip_runtime.h>

// H=256, N1=80000, N2=20000, E1=300000. Layer 0 of the reference is dead code.
// Pipeline: prep (zero cntpair + k-panel weight build) -> count_rank ->
// gemm0 h=x@Wg+bg (bf16 MFMA; scan fused) -> edge_scatter -> gat_sage ->
// sage_fin -> gemm1 (+bias+rownorm).
// R14 GEMM: revert to the R10 shape (128x256 tile, 512thr/8 waves 2x4,
// BK=32, 1 barrier/K-step) -- best total (144.5us) of all variants -- and fix
// its one defect: B was a 512B-strided gather. Weights now live in k-panel
// layout Bp[k/8][col][8], so B fragments load DIRECTLY from global as 4x256B
// contiguous segments (no B LDS; L2-resident). LDS = A-only dbuf (20KB).
// A prefetch issues at TOP of K-step so the barrier vmcnt-drain has a full
// K-step of cover. K templated (256/512) for full unroll.
// NOTE: rocprof per-dispatch dur is inflated (serialized replay); optimize
// against harness total only.

#define NS 80000
#define ND 20000

typedef float   float4v  __attribute__((ext_vector_type(4)));
typedef float   f32x4    __attribute__((ext_vector_type(4)));
typedef __bf16  bf16x8   __attribute__((ext_vector_type(8)));
typedef unsigned short ushort8v __attribute__((ext_vector_type(8)));
typedef unsigned short ushort2v __attribute__((ext_vector_type(2)));
typedef int     int4v    __attribute__((ext_vector_type(4)));

union frag_u { ushort8v u; bf16x8 b; };

__device__ __forceinline__ float us2f(unsigned short u) {
    union { unsigned int i; float f; } x; x.i = ((unsigned)u) << 16; return x.f;
}
__device__ __forceinline__ unsigned short f2us(float f) {
    union { __bf16 b; unsigned short u; } x; x.b = (__bf16)f; return x.u;
}
__device__ __forceinline__ float lrelu02(float x) { return x > 0.f ? x : 0.2f * x; }

// ---------------------------------------------------------------------------
// prep: blocks 0..255 -> Wgp (k-panel of Wg^T); 256..511 -> Wcp (k-panel of
// [Wl;Wr]^T); 512.. -> zero cntpair.
// k-panel layout: Bp[(k>>3)*256 + col]*8 + (k&7)] = B^T[col][k]
// ---------------------------------------------------------------------------
__global__ __launch_bounds__(256) void prep_misc(
    const float* __restrict__ Wg, const float* __restrict__ Wl,
    const float* __restrict__ Wr, unsigned short* __restrict__ Wgp,
    unsigned short* __restrict__ Wcp, int* __restrict__ zerop, int nz4)
{
    const int b = blockIdx.x, t = threadIdx.x;
    if (b < 256) {
        const int n = b;               // col
        const int k = t;               // 0..255
        Wgp[(((k >> 3) * 256) + n) * 8 + (k & 7)] = f2us(Wg[k * 256 + n]);
    } else if (b < 512) {
        const int n = b - 256;
        const int k0 = t;              // Wl part (k = t)
        const int k1 = t + 256;        // Wr part
        Wcp[(((k0 >> 3) * 256) + n) * 8 + (k0 & 7)] = f2us(Wl[t * 256 + n]);
        Wcp[(((k1 >> 3) * 256) + n) * 8 + (k1 & 7)] = f2us(Wr[t * 256 + n]);
    } else {
        const int i = (b - 512) * 256 + t;
        if (i < nz4) ((int4v*)zerop)[i] = (int4v){0, 0, 0, 0};
    }
}

// ---------------------------------------------------------------------------
// count + rank within class
// ---------------------------------------------------------------------------
__global__ void count_rank(const int* __restrict__ src, const int* __restrict__ dst,
                           int* __restrict__ cntpair, int* __restrict__ rank, int E)
{
    const int i = blockIdx.x * 256 + threadIdx.x;
    if (i < E) {
        const int d = dst[i];
        const int cls = (src[i] < ND) ? 0 : 1;
        rank[i] = atomicAdd(&cntpair[2 * d + cls], 1);
    }
}

// ---------------------------------------------------------------------------
// bf16 MFMA GEMM: C[M,256] = A[M,KC] @ Bp (k-panel of B^T)
// 512 thr = 8 waves (2 row x 4 col); tile 128x256; BK=32; KC templated.
// A-only dbuf LDS (20KB); B frags DIRECT from global k-panel (coalesced
// 4x256B per instruction); 1 barrier per K-step; A(kt+1) issued at top.
// EPI=0: write bf16 (h+bg) + fused al_s/al_d dots. SCAN: extra block scans.
// EPI=1: +bias, row-L2-normalize, f32 out (rows guarded).
// AF32: A is f32 (x), cvt during staging; M%128==0 assumed for AF32 path.
// ---------------------------------------------------------------------------
template <int EPI, bool AF32, bool SCAN, int KC>
__global__ __launch_bounds__(512) void gemm_mfma(
    const void* __restrict__ Av, const unsigned short* __restrict__ Bp,
    int M,
    unsigned short* __restrict__ hb_out,
    const float* __restrict__ avs, const float* __restrict__ avd,
    float* __restrict__ al_s, float* __restrict__ al_d,
    const float* __restrict__ bias, float* __restrict__ outp,
    int nblk, const int* __restrict__ cntpair, int* __restrict__ ptrp)
{
    __shared__ __align__(16) unsigned short Als[2][128][40];
    __shared__ float red0[128];
    __shared__ float red1[128];
    __shared__ int   part[512];

    if (SCAN && (int)blockIdx.x >= nblk) {
        const int tid = threadIdx.x;
        const int chunk = (ND + 511) / 512;
        const int i0 = tid * chunk;
        const int i1 = min(i0 + chunk, ND);
        int s = 0;
        for (int i = i0; i < i1; ++i) s += cntpair[2*i] + cntpair[2*i+1];
        part[tid] = s;
        __syncthreads();
        for (int off = 1; off < 512; off <<= 1) {
            const int t = (tid >= off) ? part[tid - off] : 0;
            __syncthreads();
            part[tid] += t;
            __syncthreads();
        }
        int run = tid ? part[tid - 1] : 0;
        for (int i = i0; i < i1; ++i) { ptrp[i] = run; run += cntpair[2*i] + cntpair[2*i+1]; }
        if (tid == 511) ptrp[ND] = part[511];
        return;
    }

    const int tid  = threadIdx.x;
    const int lane = tid & 63;
    const int wid  = tid >> 6;
    const int wr   = wid >> 2;      // 0..1 : 64-row half
    const int wc   = wid & 3;       // 0..3 : 64-col quarter
    const int row0 = blockIdx.x * 128;
    const int lg   = lane >> 4;     // 0..3
    const int lm   = lane & 15;

    f32x4 acc[4][4] = {};
    constexpr int nk = KC >> 5;

    // A staging: thread -> row tid>>2 (0..127), k-offset (tid&3)*8
    const int arow = tid >> 2;
    const int akof = (tid & 3) * 8;

    float4v ar0, ar1;                   // AF32 raw (32B/thread)
    ushort8v ai;                        // bf16 raw (16B/thread)

    auto loadA = [&](int kt) {
        const int k0 = kt * 32 + akof;
        const int grow = row0 + arow;
        if constexpr (AF32) {
            const float* p = (const float*)Av + (size_t)grow * KC + k0;
            ar0 = *(const float4v*)p;
            ar1 = *(const float4v*)(p + 4);
        } else {
            if (grow < M)
                ai = *(const ushort8v*)((const unsigned short*)Av + (size_t)grow * KC + k0);
            else
                ai = (ushort8v){0,0,0,0,0,0,0,0};
        }
    };
    auto storeA = [&](int b) {
        if constexpr (AF32) {
            ushort8v t;
            t[0] = f2us(ar0[0]); t[1] = f2us(ar0[1]); t[2] = f2us(ar0[2]); t[3] = f2us(ar0[3]);
            t[4] = f2us(ar1[0]); t[5] = f2us(ar1[1]); t[6] = f2us(ar1[2]); t[7] = f2us(ar1[3]);
            *(ushort8v*)&Als[b][arow][akof] = t;
        } else {
            *(ushort8v*)&Als[b][arow][akof] = ai;
        }
    };

    loadA(0); storeA(0); __syncthreads();
    int cur = 0;

#pragma unroll
    for (int kt = 0; kt < nk; ++kt) {
        if (kt + 1 < nk) loadA(kt + 1);      // issued early; drained at barrier
        // B frags direct from k-panel global (coalesced, L2-resident)
        frag_u bf[4];
#pragma unroll
        for (int n = 0; n < 4; ++n)
            bf[n].u = *(const ushort8v*)(Bp +
                ((size_t)(kt*4 + lg) * 256 + wc*64 + n*16 + lm) * 8);
        frag_u af[4];
#pragma unroll
        for (int m = 0; m < 4; ++m)
            af[m].u = *(const ushort8v*)&Als[cur][wr*64 + m*16 + lm][lg*8];
#pragma unroll
        for (int m = 0; m < 4; ++m)
#pragma unroll
            for (int n = 0; n < 4; ++n)
                acc[m][n] = __builtin_amdgcn_mfma_f32_16x16x32_bf16(
                    af[m].b, bf[n].b, acc[m][n], 0, 0, 0);
        if (kt + 1 < nk) {
            storeA(cur ^ 1);
            __syncthreads();
            cur ^= 1;
        }
    }

    if constexpr (EPI == 0) {
        if (tid < 128) { red0[tid] = 0.f; red1[tid] = 0.f; }
        __syncthreads();
        float asv[4], adv[4], bgv[4];
#pragma unroll
        for (int n = 0; n < 4; ++n) {
            const int col = wc*64 + n*16 + lm;
            asv[n] = avs[col]; adv[n] = avd[col]; bgv[n] = bias[col];
        }
#pragma unroll
        for (int m = 0; m < 4; ++m) {
#pragma unroll
            for (int j = 0; j < 4; ++j) {
                const int lr = wr*64 + m*16 + lg*4 + j;
                float ps = 0.f, pd = 0.f;
#pragma unroll
                for (int n = 0; n < 4; ++n) {
                    const float v = acc[m][n][j];
                    ps += v * asv[n]; pd += v * adv[n];
                    hb_out[(size_t)(row0 + lr) * 256 + wc*64 + n*16 + lm] = f2us(v + bgv[n]);
                }
#pragma unroll
                for (int off = 1; off < 16; off <<= 1) {
                    ps += __shfl_xor(ps, off);
                    pd += __shfl_xor(pd, off);
                }
                if (lm == 0) { atomicAdd(&red0[lr], ps); atomicAdd(&red1[lr], pd); }
            }
        }
        __syncthreads();
        if (tid < 128) { al_s[row0 + tid] = red0[tid]; al_d[row0 + tid] = red1[tid]; }
    } else {
        if (tid < 128) red0[tid] = 0.f;
        __syncthreads();
        float bv[4];
#pragma unroll
        for (int n = 0; n < 4; ++n) bv[n] = bias[wc*64 + n*16 + lm];
#pragma unroll
        for (int m = 0; m < 4; ++m) {
#pragma unroll
            for (int j = 0; j < 4; ++j) {
                const int lr = wr*64 + m*16 + lg*4 + j;
                float ss = 0.f;
#pragma unroll
                for (int n = 0; n < 4; ++n) {
                    const float v = acc[m][n][j] + bv[n];
                    acc[m][n][j] = v;
                    ss += v * v;
                }
#pragma unroll
                for (int off = 1; off < 16; off <<= 1) ss += __shfl_xor(ss, off);
                if (lm == 0) atomicAdd(&red0[lr], ss);
            }
        }
        __syncthreads();
#pragma unroll
        for (int m = 0; m < 4; ++m) {
#pragma unroll
            for (int j = 0; j < 4; ++j) {
                const int lr = wr*64 + m*16 + lg*4 + j;
                const int grow = row0 + lr;
                if (grow < M) {
                    const float inv = 1.0f / fmaxf(sqrtf(red0[lr]), 1e-12f);
#pragma unroll
                    for (int n = 0; n < 4; ++n)
                        outp[(size_t)grow * 256 + wc*64 + n*16 + lm] = acc[m][n][j] * inv;
                }
            }
        }
    }
}

// ---------------------------------------------------------------------------
// scatter: atomic-free via rank; class-ordered (s<ND first within each row)
// ---------------------------------------------------------------------------
__global__ void edge_scatter(const int* __restrict__ src, const int* __restrict__ dst,
                             const int* __restrict__ ptrp, const int* __restrict__ rank,
                             const int* __restrict__ cntpair,
                             int* __restrict__ ssort, int E)
{
    const int i = blockIdx.x * 256 + threadIdx.x;
    if (i < E) {
        const int d = dst[i];
        const int s = src[i];
        const int base = ptrp[d];
        const int pos = (s < ND) ? base + rank[i]
                                 : base + cntpair[2 * d] + rank[i];
        ssort[pos] = s;
    }
}

// ---------------------------------------------------------------------------
// Fused GAT aggregation + SAGE partial sum over s>=ND neighbors.
// Block=128: 4 slots x 32 lanes; lane holds 8 channels. Weight w computed
// inline (al_s L2-resident broadcast). z folded into gather loop; unroll-2.
// Writes h1a into hcat[:,256:512] and s>=ND partial sum into hcat[:,0:256].
// ---------------------------------------------------------------------------
__global__ __launch_bounds__(128) void gat_sage(
    const unsigned short* __restrict__ hb, const float* __restrict__ al_s,
    const float* __restrict__ al_d, const int* __restrict__ ssort,
    const int* __restrict__ ptrp, unsigned short* __restrict__ hcat)
{
    __shared__ float ldsg[4][264];
    __shared__ float ldss[4][264];
    __shared__ float zp[4];
    const int v    = blockIdx.x;
    const int tid  = threadIdx.x;
    const int slot = tid >> 5;      // 0..3
    const int l32  = tid & 31;
    const int c0   = l32 * 8;
    const int p0 = ptrp[v], p1 = ptrp[v + 1];

    const float ad     = al_d[v];
    const float w_self = __expf(lrelu02(al_s[v] + ad));

    float accg[8], accs[8];
    float zpart = 0.f;
#pragma unroll
    for (int j = 0; j < 8; ++j) accs[j] = 0.f;
    if (slot == 0) {
        const ushort8v hv = *(const ushort8v*)&hb[(size_t)v * 256 + c0];
#pragma unroll
        for (int j = 0; j < 8; ++j) accg[j] = w_self * us2f(hv[j]);
    } else {
#pragma unroll
        for (int j = 0; j < 8; ++j) accg[j] = 0.f;
    }

    int p = p0 + slot;
    for (; p + 4 < p1; p += 8) {            // 2 edges per iteration
        const int s0 = ssort[p];
        const int s1 = ssort[p + 4];
        const float w0 = __expf(lrelu02(al_s[s0] + ad));
        const float w1 = __expf(lrelu02(al_s[s1] + ad));
        const ushort8v h0 = *(const ushort8v*)&hb[(size_t)s0 * 256 + c0];
        const ushort8v h1 = *(const ushort8v*)&hb[(size_t)s1 * 256 + c0];
        zpart += w0 + w1;
        const bool g0 = (s0 >= ND), g1 = (s1 >= ND);
#pragma unroll
        for (int j = 0; j < 8; ++j) {
            const float f0 = us2f(h0[j]);
            const float f1 = us2f(h1[j]);
            accg[j] = fmaf(w0, f0, accg[j]);
            accg[j] = fmaf(w1, f1, accg[j]);
            accs[j] += (g0 ? f0 : 0.f) + (g1 ? f1 : 0.f);
        }
    }
    if (p < p1) {                           // tail edge
        const int s0 = ssort[p];
        const float w0 = __expf(lrelu02(al_s[s0] + ad));
        const ushort8v h0 = *(const ushort8v*)&hb[(size_t)s0 * 256 + c0];
        zpart += w0;
        const bool g0 = (s0 >= ND);
#pragma unroll
        for (int j = 0; j < 8; ++j) {
            const float f0 = us2f(h0[j]);
            accg[j] = fmaf(w0, f0, accg[j]);
            accs[j] += g0 ? f0 : 0.f;
        }
    }

    if (l32 == 0) zp[slot] = zpart;
    *(f32x4*)&ldsg[slot][c0]     = (f32x4){accg[0], accg[1], accg[2], accg[3]};
    *(f32x4*)&ldsg[slot][c0 + 4] = (f32x4){accg[4], accg[5], accg[6], accg[7]};
    *(f32x4*)&ldss[slot][c0]     = (f32x4){accs[0], accs[1], accs[2], accs[3]};
    *(f32x4*)&ldss[slot][c0 + 4] = (f32x4){accs[4], accs[5], accs[6], accs[7]};
    __syncthreads();

    const float inv_z = 1.0f / (w_self + zp[0] + zp[1] + zp[2] + zp[3]);
    const int c = tid * 2;          // 2 channels per thread
    float rg0 = 0.f, rg1 = 0.f, rs0 = 0.f, rs1 = 0.f;
#pragma unroll
    for (int s2 = 0; s2 < 4; ++s2) {
        rg0 += ldsg[s2][c];     rg1 += ldsg[s2][c + 1];
        rs0 += ldss[s2][c];     rs1 += ldss[s2][c + 1];
    }
    *(ushort2v*)&hcat[(size_t)v * 512 + 256 + c] =
        (ushort2v){f2us(rg0 * inv_z), f2us(rg1 * inv_z)};
    *(ushort2v*)&hcat[(size_t)v * 512 + c] =
        (ushort2v){f2us(rs0), f2us(rs1)};               // psum (pre-mean)
}

// ---------------------------------------------------------------------------
// SAGE finisher: psum (bf16, in hcat[:,0:256]) += s<ND h1a gathers (class-
// ordered CSR: only first cntpair[2v] edges, no branch); divide by degree.
// ---------------------------------------------------------------------------
__global__ __launch_bounds__(256) void sage_fin(
    const int* __restrict__ ssort, const int* __restrict__ ptrp,
    const int* __restrict__ cntpair, unsigned short* __restrict__ hcat)
{
    const int tid   = threadIdx.x;
    const int g     = tid >> 6;                 // 0..3 (one wave per dst)
    const int v     = blockIdx.x * 4 + g;
    const int slot2 = (tid >> 5) & 1;
    const int l32   = tid & 31;
    const int c0    = l32 * 8;
    const int p0  = ptrp[v];
    const int p1l = p0 + cntpair[2 * v];        // lt-edges only
    const int deg = ptrp[v + 1] - p0;

    float acc[8];
    if (slot2 == 0) {
        const ushort8v pv = *(const ushort8v*)&hcat[(size_t)v * 512 + c0];
#pragma unroll
        for (int j = 0; j < 8; ++j) acc[j] = us2f(pv[j]);
    } else {
#pragma unroll
        for (int j = 0; j < 8; ++j) acc[j] = 0.f;
    }
    int p = p0 + slot2;
    for (; p + 2 < p1l; p += 4) {               // 2 edges per iteration
        const int s0 = ssort[p];
        const int s1 = ssort[p + 2];
        const ushort8v h0 = *(const ushort8v*)&hcat[(size_t)s0 * 512 + 256 + c0];
        const ushort8v h1 = *(const ushort8v*)&hcat[(size_t)s1 * 512 + 256 + c0];
#pragma unroll
        for (int j = 0; j < 8; ++j) acc[j] += us2f(h0[j]) + us2f(h1[j]);
    }
    if (p < p1l) {
        const int s0 = ssort[p];
        const ushort8v h0 = *(const ushort8v*)&hcat[(size_t)s0 * 512 + 256 + c0];
#pragma unroll
        for (int j = 0; j < 8; ++j) acc[j] += us2f(h0[j]);
    }
#pragma unroll
    for (int j = 0; j < 8; ++j) acc[j] += __shfl_xor(acc[j], 32);

    const float inv = (deg > 0) ? 1.0f / (float)deg : 0.f;
    if (slot2 == 0) {
        ushort8v o;
#pragma unroll
        for (int j = 0; j < 8; ++j) o[j] = f2us(acc[j] * inv);
        *(ushort8v*)&hcat[(size_t)v * 512 + c0] = o;
    }
}

// ---------------------------------------------------------------------------
extern "C" void kernel_launch(void* const* d_in, const int* in_sizes, int n_in,
                              void* d_out, int out_size, void* d_ws, size_t ws_size,
                              hipStream_t stream)
{
    const float* x    = (const float*)d_in[0];
    const float* Wg   = (const float*)d_in[1];
    const float* asrc = (const float*)d_in[2];
    const float* adst = (const float*)d_in[3];
    const float* bg   = (const float*)d_in[4];
    const float* Wl1  = (const float*)d_in[8];
    const float* bl1  = (const float*)d_in[9];
    const float* Wr1  = (const float*)d_in[10];
    const int*   src1 = (const int*)d_in[13];
    const int*   dst1 = (const int*)d_in[14];
    const int E1 = in_sizes[13];

    // workspace
    char* w = (char*)d_ws;
    unsigned short* hb   = (unsigned short*)w; w += (size_t)NS * 256 * 2;   // 40.96 MB
    unsigned short* hcat = (unsigned short*)w; w += (size_t)ND * 512 * 2;   // 20.48 MB
    unsigned short* Wgp  = (unsigned short*)w; w += 256 * 256 * 2;          // k-panel Wg^T
    unsigned short* Wcp  = (unsigned short*)w; w += 256 * 512 * 2;          // k-panel [Wl;Wr]^T
    float* al_s   = (float*)w; w += (size_t)NS * 4;
    float* al_d   = (float*)w; w += (size_t)NS * 4;
    int* cntpair  = (int*)w;   w += (size_t)2 * ND * 4;
    int* ptrv     = (int*)w;   w += (size_t)(ND + 4) * 4;
    int* rank     = (int*)w;   w += (size_t)E1 * 4;
    int* ssort    = (int*)w;   w += (size_t)E1 * 4;

    const dim3 b256(256), b512(512);
    const int nz4 = 2 * ND / 4;   // cntpair in int4s

    prep_misc<<<dim3(512 + (nz4 + 255) / 256), b256, 0, stream>>>(
        Wg, Wl1, Wr1, Wgp, Wcp, cntpair, nz4);

    count_rank<<<dim3((E1 + 255) / 256), b256, 0, stream>>>(
        src1, dst1, cntpair, rank, E1);

    // h = x @ Wg + bg (bf16) with fused pre-bias al_s/al_d; scan fused
    const int nblk0 = NS / 128;
    gemm_mfma<0, true, true, 256><<<dim3(nblk0 + 1), b512, 0, stream>>>(
        x, Wgp, NS, hb, asrc, adst, al_s, al_d, bg, nullptr,
        nblk0, cntpair, ptrv);

    edge_scatter<<<dim3((E1 + 255) / 256), b256, 0, stream>>>(
        src1, dst1, ptrv, rank, cntpair, ssort, E1);

    // fused GAT aggregate + SAGE s>=ND partial sum (psum bf16 in-place)
    gat_sage<<<dim3(ND), dim3(128), 0, stream>>>(hb, al_s, al_d, ssort,
                                                 ptrv, hcat);
    // SAGE finisher: s<ND h1a gathers + divide
    sage_fin<<<dim3(ND / 4), b256, 0, stream>>>(ssort, ptrv, cntpair, hcat);

    // out = normalize([mean|h1a] @ [Wl1;Wr1] + bl1)
    gemm_mfma<1, false, false, 512><<<dim3((ND + 127) / 128), b512, 0, stream>>>(
        hcat, Wcp, ND, nullptr, nullptr, nullptr, nullptr, nullptr,
        bl1, (float*)d_out, 0, nullptr, nullptr);
}